// Round 1
// baseline (713.592 us; speedup 1.0000x reference)
//
#include <hip/hip_runtime.h>
#include <hip/hip_bf16.h>

#define HW 512
#define IC 64
#define OC 64
#define NB 4
#define KDIM 576  /* 9 taps * 64 input channels */

typedef short s16x8 __attribute__((ext_vector_type(8)));
typedef float f32x4 __attribute__((ext_vector_type(4)));

// ---------------------------------------------------------------------------
// Kernel 1: style modulation + demodulation -> bf16 weights, layout
// wd[b][o][tap][i]  (k = tap*64 + i, contiguous i within tap)
// one wave per (b,o); lane = input channel i
// ---------------------------------------------------------------------------
__global__ __launch_bounds__(64) void demod_kernel(
    const float* __restrict__ weight,   // [O][I][3][3]
    const float* __restrict__ style,    // [B][I]
    __hip_bfloat16* __restrict__ wd)    // [B][O][9][64]
{
    const int bo = blockIdx.x;
    const int b = bo >> 6;
    const int o = bo & 63;
    const int i = threadIdx.x;  // 0..63

    const float st = style[b * IC + i];
    float v[9];
    float s = 0.f;
#pragma unroll
    for (int t = 0; t < 9; ++t) {
        const float w = weight[(o * IC + i) * 9 + t] * st;
        v[t] = w;
        s += w * w;
    }
    // reduce across the 64-lane wave
#pragma unroll
    for (int off = 32; off >= 1; off >>= 1) s += __shfl_xor(s, off);
    const float rs = 1.0f / sqrtf(1e-8f + s);
#pragma unroll
    for (int t = 0; t < 9; ++t)
        wd[((b * OC + o) * 9 + t) * IC + i] = __float2bfloat16(v[t] * rs);
}

// ---------------------------------------------------------------------------
// Kernel 2: NCHW fp32 -> NHWC bf16  (t[b][y][x][i])
// block: one (b, y, 64-wide x tile); LDS transpose 64i x 64x
// ---------------------------------------------------------------------------
__global__ __launch_bounds__(256) void nchw_to_nhwc_bf16(
    const float* __restrict__ in,       // [B][I][H][W]
    __hip_bfloat16* __restrict__ t)     // [B][H][W][I]
{
    __shared__ __hip_bfloat16 lds[64][72];  // [x][i], i padded 64->72
    const int xb = blockIdx.x * 64;
    const int y = blockIdx.y;
    const int b = blockIdx.z;
    const int tid = threadIdx.x;

#pragma unroll
    for (int it = 0; it < 4; ++it) {
        const int idx = it * 256 + tid;   // 0..1023
        const int i = idx >> 4;           // 0..63  input channel
        const int xq = idx & 15;          // 0..15  float4 group along x
        const float4 v = *(const float4*)(in +
            (((long)(b * IC + i) * HW + y) * HW + xb + xq * 4));
        lds[xq * 4 + 0][i] = __float2bfloat16(v.x);
        lds[xq * 4 + 1][i] = __float2bfloat16(v.y);
        lds[xq * 4 + 2][i] = __float2bfloat16(v.z);
        lds[xq * 4 + 3][i] = __float2bfloat16(v.w);
    }
    __syncthreads();
    unsigned short* tp = (unsigned short*)t;
#pragma unroll
    for (int it = 0; it < 2; ++it) {
        const int idx = it * 256 + tid;   // 0..511
        const int x = idx >> 3;           // 0..63
        const int ig = idx & 7;           // 0..7 (8 bf16 = 16B each)
        const uint4 w = *(const uint4*)&lds[x][ig * 8];
        *(uint4*)(tp + (((long)(b * HW + y) * HW + xb + x) * IC + ig * 8)) = w;
    }
}

// ---------------------------------------------------------------------------
// Kernel 3: implicit-GEMM conv via mfma_f32_16x16x32_bf16.
// Per batch: C[o, pix] = sum_k W[o,k] * X[k,pix], M=64, K=576.
// Block = 4 waves; wave tile = 64 (all o) x 64 pixels (one row y).
// No LDS, no barriers: A (weights) and B (NHWC input) read via L1/L2.
// A layout: lane m=lane&15, k=quad*8+j.  C/D: col=lane&15, row=quad*4+reg.
// ---------------------------------------------------------------------------
__global__ __launch_bounds__(256, 3) void conv_mfma(
    const __hip_bfloat16* __restrict__ tin,  // [B][H][W][I]
    const __hip_bfloat16* __restrict__ wd,   // [B][O][9][64]
    float* __restrict__ out)                 // [B][O][H][W]
{
    const int tid = threadIdx.x;
    const int wave = tid >> 6;
    const int lane = tid & 63;
    const int l15 = lane & 15;
    const int quad = lane >> 4;
    const int b = blockIdx.z;
    const int y = blockIdx.y;
    const int x0 = blockIdx.x * 256 + wave * 64;  // wave's pixel base

    const unsigned short* wptr = (const unsigned short*)wd + (long)b * OC * KDIM;
    const unsigned short* tb = (const unsigned short*)tin + (long)b * HW * HW * IC;

    f32x4 acc[4][4];
#pragma unroll
    for (int mt = 0; mt < 4; ++mt)
#pragma unroll
        for (int nt = 0; nt < 4; ++nt)
            acc[mt][nt] = (f32x4){0.f, 0.f, 0.f, 0.f};

#pragma unroll
    for (int s = 0; s < 18; ++s) {
        const int tap = s >> 1;            // 0..8
        const int ky = tap / 3;
        const int kx = tap % 3;
        const int yin = y + ky - 1;
        if ((unsigned)yin >= (unsigned)HW) continue;  // block-uniform zero pad

        // A fragments: k = s*32 + quad*8 + j  (j=0..7 contiguous)
        s16x8 afr[4];
#pragma unroll
        for (int mt = 0; mt < 4; ++mt) {
            const int o = mt * 16 + l15;
            afr[mt] = *(const s16x8*)(wptr + o * KDIM + s * 32 + quad * 8);
        }
        // B fragments: 8 consecutive input channels at one pixel
        const int i0 = (s & 1) * 32 + quad * 8;
        const unsigned short* trow = tb + (long)yin * HW * IC;
        s16x8 bfr[4];
#pragma unroll
        for (int nt = 0; nt < 4; ++nt) {
            const int xin = x0 + nt * 16 + l15 + kx - 1;
            const bool ok = (unsigned)xin < (unsigned)HW;
            s16x8 v = {};
            if (ok) v = *(const s16x8*)(trow + xin * IC + i0);
            bfr[nt] = v;
        }
#pragma unroll
        for (int mt = 0; mt < 4; ++mt)
#pragma unroll
            for (int nt = 0; nt < 4; ++nt)
                acc[mt][nt] = __builtin_amdgcn_mfma_f32_16x16x32_bf16(
                    afr[mt], bfr[nt], acc[mt][nt], 0, 0, 0);
    }

    // epilogue: D row = o (quad*4+reg), col = pixel x
#pragma unroll
    for (int mt = 0; mt < 4; ++mt) {
#pragma unroll
        for (int r = 0; r < 4; ++r) {
            const int o = mt * 16 + quad * 4 + r;
            float* orow = out + ((long)(b * OC + o) * HW + y) * HW;
#pragma unroll
            for (int nt = 0; nt < 4; ++nt)
                orow[x0 + nt * 16 + l15] = acc[mt][nt][r];
        }
    }
}

// ---------------------------------------------------------------------------
extern "C" void kernel_launch(void* const* d_in, const int* in_sizes, int n_in,
                              void* d_out, int out_size, void* d_ws, size_t ws_size,
                              hipStream_t stream) {
    const float* inp = (const float*)d_in[0];     // [4][64][512][512]
    const float* style = (const float*)d_in[1];   // [4][64]
    const float* weight = (const float*)d_in[2];  // [64][64][3][3]
    float* out = (float*)d_out;                   // [4][64][512][512]

    __hip_bfloat16* wd = (__hip_bfloat16*)d_ws;                       // 294,912 B
    __hip_bfloat16* tin = (__hip_bfloat16*)((char*)d_ws + 0x60000);   // 134.2 MB

    demod_kernel<<<dim3(NB * OC), dim3(64), 0, stream>>>(weight, style, wd);
    nchw_to_nhwc_bf16<<<dim3(HW / 64, HW, NB), dim3(256), 0, stream>>>(inp, tin);
    conv_mfma<<<dim3(HW / 256, HW, NB), dim3(256), 0, stream>>>(tin, wd, out);
}

// Round 2
// 654.153 us; speedup vs baseline: 1.0909x; 1.0909x over previous
//
#include <hip/hip_runtime.h>
#include <hip/hip_bf16.h>

#define HW 512
#define IC 64
#define OC 64
#define NB 4
#define KDIM 576   /* 9 taps * 64 input channels */
#define LROW 258   /* 256 px + 2 halo */

typedef short s16x8 __attribute__((ext_vector_type(8)));
typedef float f32x4 __attribute__((ext_vector_type(4)));

// ---------------------------------------------------------------------------
// Kernel 1: style modulation + demodulation -> bf16 weights wd[b][o][tap][i]
// ---------------------------------------------------------------------------
__global__ __launch_bounds__(64) void demod_kernel(
    const float* __restrict__ weight,   // [O][I][3][3]
    const float* __restrict__ style,    // [B][I]
    __hip_bfloat16* __restrict__ wd)    // [B][O][9][64]
{
    const int bo = blockIdx.x;
    const int b = bo >> 6;
    const int o = bo & 63;
    const int i = threadIdx.x;

    const float st = style[b * IC + i];
    float v[9];
    float s = 0.f;
#pragma unroll
    for (int t = 0; t < 9; ++t) {
        const float w = weight[(o * IC + i) * 9 + t] * st;
        v[t] = w;
        s += w * w;
    }
#pragma unroll
    for (int off = 32; off >= 1; off >>= 1) s += __shfl_xor(s, off);
    const float rs = 1.0f / sqrtf(1e-8f + s);
#pragma unroll
    for (int t = 0; t < 9; ++t)
        wd[((b * OC + o) * 9 + t) * IC + i] = __float2bfloat16(v[t] * rs);
}

// ---------------------------------------------------------------------------
// Kernel 2: NCHW fp32 -> NHWC bf16.  Tile: 64 ch x 128 px of one row y.
// LDS bf16 [64][130]: stage writes 2x b32 (2-way banks), reads scalar u16
// (2-way banks), stores fully coalesced 16B.
// ---------------------------------------------------------------------------
__global__ __launch_bounds__(256) void nchw_to_nhwc_bf16(
    const float* __restrict__ in,       // [B][I][H][W]
    __hip_bfloat16* __restrict__ t)     // [B][H][W][I]
{
    __shared__ unsigned short lds[64 * 130];
    const int tid = threadIdx.x;
    const int xb = blockIdx.x * 128;
    const int y = blockIdx.y;
    const int b = blockIdx.z;

#pragma unroll
    for (int it = 0; it < 8; ++it) {
        const int idx = it * 256 + tid;
        const int i = idx >> 5;          // channel 0..63
        const int xq = idx & 31;         // float4 group along x
        const float4 v = *(const float4*)(in +
            (((long)(b * IC + i) * HW + y) * HW + xb + xq * 4));
        __hip_bfloat16 h0 = __float2bfloat16(v.x), h1 = __float2bfloat16(v.y);
        __hip_bfloat16 h2 = __float2bfloat16(v.z), h3 = __float2bfloat16(v.w);
        unsigned p01 = ((unsigned)*(unsigned short*)&h1 << 16) | *(unsigned short*)&h0;
        unsigned p23 = ((unsigned)*(unsigned short*)&h3 << 16) | *(unsigned short*)&h2;
        *(unsigned*)&lds[i * 130 + xq * 4] = p01;
        *(unsigned*)&lds[i * 130 + xq * 4 + 2] = p23;
    }
    __syncthreads();
    unsigned short* tp = (unsigned short*)t;
#pragma unroll
    for (int it = 0; it < 4; ++it) {
        const int idx = it * 256 + tid;
        const int x = idx >> 3;          // 0..127
        const int g = idx & 7;           // 8-ch group
        unsigned r[4];
#pragma unroll
        for (int cp = 0; cp < 4; ++cp) {
            unsigned lo = lds[(g * 8 + cp * 2) * 130 + x];
            unsigned hi = lds[(g * 8 + cp * 2 + 1) * 130 + x];
            r[cp] = (hi << 16) | lo;
        }
        uint4 o4 = {r[0], r[1], r[2], r[3]};
        *(uint4*)(tp + (((long)(b * HW + y) * HW + xb + x) * IC + g * 8)) = o4;
    }
}

// ---------------------------------------------------------------------------
// Kernel 3: implicit-GEMM conv. Block = 4 waves, tile 64 O x 256 px (row y).
// Input staged in LDS (3 rows x 258 px x 32 ch bf16, two channel-half
// passes); zero-pad handled at staging, so the MFMA loop is branch-free.
// A (weights) from global (L1/L2-resident). XCD-swizzled 1-D grid.
// ---------------------------------------------------------------------------
__global__ __launch_bounds__(256, 3) void conv_mfma(
    const __hip_bfloat16* __restrict__ tin,  // [B][H][W][I]
    const __hip_bfloat16* __restrict__ wd,   // [B][O][9][64]
    float* __restrict__ out)                 // [B][O][H][W]
{
    __shared__ unsigned short bin[3 * LROW * 32];  // 49,536 B

    const int tid = threadIdx.x;
    const int wave = tid >> 6, lane = tid & 63;
    const int l15 = lane & 15, quad = lane >> 4;

    // XCD-aware swizzle: xcd = id&7 -> (b, y-half); slots walk y contiguously
    const int id = blockIdx.x;               // 0..4095
    const int xcd = id & 7, slot = id >> 3;  // slot 0..511
    const int b = xcd >> 1;
    const int y = ((xcd & 1) << 8) | (slot >> 1);
    const int xb = (slot & 1) << 8;          // 0 or 256
    const int x0w = wave << 6;               // wave px base within block

    const unsigned short* wptr = (const unsigned short*)wd + (long)b * OC * KDIM;
    const unsigned short* tb = (const unsigned short*)tin + (long)b * HW * HW * IC;

    f32x4 acc[4][4];
#pragma unroll
    for (int mt = 0; mt < 4; ++mt)
#pragma unroll
        for (int nt = 0; nt < 4; ++nt)
            acc[mt][nt] = (f32x4){0.f, 0.f, 0.f, 0.f};

    for (int c = 0; c < 2; ++c) {
        // ---- stage 3 rows x 258 px x 32ch (16B chunks; 1032 chunks/row) ----
#pragma unroll
        for (int it = 0; it < 13; ++it) {
            const int ci = it * 256 + tid;
            if (ci < 3096) {
                const int r = ci / 1032;
                const int q = ci - r * 1032;
                const int p = q >> 2;        // px 0..257
                const int cg = q & 3;        // 16B group within 32ch
                const int xg = xb + p - 1;
                const int yg = y + r - 1;
                uint4 v = {0u, 0u, 0u, 0u};
                if (((unsigned)xg < (unsigned)HW) & ((unsigned)yg < (unsigned)HW))
                    v = *(const uint4*)(tb + ((long)yg * HW + xg) * IC + c * 32 + cg * 8);
                *(uint4*)(&bin[(r * LROW + p) * 32 + cg * 8]) = v;
            }
        }
        __syncthreads();

        // ---- 9 taps, K=32 each: branch-free straight line ----
#pragma unroll
        for (int tap = 0; tap < 9; ++tap) {
            const int ky = tap / 3, kx = tap % 3;
            s16x8 afr[4], bfr[4];
#pragma unroll
            for (int mt = 0; mt < 4; ++mt)
                afr[mt] = *(const s16x8*)(wptr + (mt * 16 + l15) * KDIM +
                                          tap * 64 + c * 32 + quad * 8);
#pragma unroll
            for (int nt = 0; nt < 4; ++nt)
                bfr[nt] = *(const s16x8*)(&bin[(ky * LROW + x0w + nt * 16 + l15 + kx) * 32 +
                                               quad * 8]);
#pragma unroll
            for (int mt = 0; mt < 4; ++mt)
#pragma unroll
                for (int nt = 0; nt < 4; ++nt)
                    acc[mt][nt] = __builtin_amdgcn_mfma_f32_16x16x32_bf16(
                        afr[mt], bfr[nt], acc[mt][nt], 0, 0, 0);
        }
        __syncthreads();
    }

    // ---- epilogue: D row = o (quad*4+reg), col = pixel ----
#pragma unroll
    for (int mt = 0; mt < 4; ++mt) {
#pragma unroll
        for (int r = 0; r < 4; ++r) {
            const int o = mt * 16 + quad * 4 + r;
            float* orow = out + ((long)(b * OC + o) * HW + y) * HW + xb + x0w;
#pragma unroll
            for (int nt = 0; nt < 4; ++nt)
                orow[nt * 16 + l15] = acc[mt][nt][r];
        }
    }
}

// ---------------------------------------------------------------------------
extern "C" void kernel_launch(void* const* d_in, const int* in_sizes, int n_in,
                              void* d_out, int out_size, void* d_ws, size_t ws_size,
                              hipStream_t stream) {
    const float* inp = (const float*)d_in[0];     // [4][64][512][512]
    const float* style = (const float*)d_in[1];   // [4][64]
    const float* weight = (const float*)d_in[2];  // [64][64][3][3]
    float* out = (float*)d_out;                   // [4][64][512][512]

    __hip_bfloat16* wd = (__hip_bfloat16*)d_ws;                       // 294,912 B
    __hip_bfloat16* tin = (__hip_bfloat16*)((char*)d_ws + 0x60000);   // 134.2 MB

    demod_kernel<<<dim3(NB * OC), dim3(64), 0, stream>>>(weight, style, wd);
    nchw_to_nhwc_bf16<<<dim3(HW / 128, HW, NB), dim3(256), 0, stream>>>(inp, tin);
    conv_mfma<<<dim3(NB * HW * 2), dim3(256), 0, stream>>>(tin, wd, out);
}